// Round 1
// baseline (128.653 us; speedup 1.0000x reference)
//
#include <hip/hip_runtime.h>
#include <cstdint>

#define BATCH 256
#define DIN   512
#define DOUT  256
#define D2    128
#define NQ    16
#define NC    100
#define KFC   (D2 * D2)   // 16384

#define FC_BM 64
#define FC_KS 64
#define FC_KCHUNK (KFC / FC_KS)   // 256
#define FC_BK 32
#define FC_NBT (BATCH / FC_BM)    // 4

// ---------------------------------------------------------------------------
// K1: W2T[i][o] = 0.5*(W[2o][i] + W[2o+1][i])  -- pooled weight, transposed
// ---------------------------------------------------------------------------
__global__ __launch_bounds__(256) void k_poolw(const float* __restrict__ W,
                                               float* __restrict__ W2T) {
    int idx = blockIdx.x * 256 + threadIdx.x;   // 0 .. 65535
    int o = idx & (D2 - 1);
    int i = idx >> 7;
    W2T[(size_t)i * D2 + o] =
        0.5f * (W[(size_t)(2 * o) * DIN + i] + W[(size_t)(2 * o + 1) * DIN + i]);
}

// ---------------------------------------------------------------------------
// K2: per-batch block. Z = W2 @ X_b (128x16); G = Z^T Z; G^{-1} via
// Gauss-Jordan (SPD); E = Z G^{-1}; P2 = E Z^T  (projector onto range(Z)).
// ---------------------------------------------------------------------------
__global__ __launch_bounds__(256) void k_batch(const float* __restrict__ X,
                                               const float* __restrict__ W2T,
                                               float* __restrict__ P2) {
    __shared__ float Xs[DIN][NQ];          // 32 KB
    __shared__ float Zs[D2][NQ + 1];       // padded
    __shared__ float Es[D2][NQ + 1];
    __shared__ float Gi[NQ][2 * NQ];       // [G | I] -> [I | G^{-1}]

    int b = blockIdx.x;
    int t = threadIdx.x;
    const float* Xb = X + (size_t)b * DIN * NQ;

    // stage X_b (coalesced)
    for (int l = t; l < DIN * NQ; l += 256)
        Xs[l >> 4][l & 15] = Xb[l];
    __syncthreads();

    int o  = t & (D2 - 1);
    int qh = (t >> 7) * 8;   // 0 or 8

    // Z = W2 @ X_b : each thread owns (o, 8 q's)
    {
        float acc[8] = {};
        for (int i = 0; i < DIN; ++i) {
            float w = W2T[(size_t)i * D2 + o];   // coalesced, L2-resident
            #pragma unroll
            for (int j = 0; j < 8; ++j) acc[j] = fmaf(w, Xs[i][qh + j], acc[j]);
        }
        #pragma unroll
        for (int j = 0; j < 8; ++j) Zs[o][qh + j] = acc[j];
    }
    __syncthreads();

    // G = Z^T Z : 256 threads <-> 256 entries
    {
        int qq = t >> 4, rr = t & 15;
        float s = 0.f;
        for (int i = 0; i < D2; ++i) s = fmaf(Zs[i][qq], Zs[i][rr], s);
        Gi[qq][rr] = s;
        Gi[qq][NQ + rr] = (qq == rr) ? 1.f : 0.f;
    }
    __syncthreads();

    // Gauss-Jordan on [G | I] (SPD -> no pivoting). Thread t -> row r, cols c0,c1.
    {
        int r  = t >> 4;
        int c0 = t & 15;
        int c1 = c0 + NQ;
        for (int k = 0; k < NQ; ++k) {
            float piv = Gi[k][k];
            float fac = Gi[r][k];
            float vk0 = Gi[k][c0];
            float vk1 = Gi[k][c1];
            __syncthreads();
            float inv = 1.f / piv;
            if (r == k) {
                Gi[k][c0] = vk0 * inv;
                Gi[k][c1] = vk1 * inv;
            } else {
                float f = fac * inv;
                Gi[r][c0] = fmaf(-f, vk0, Gi[r][c0]);
                Gi[r][c1] = fmaf(-f, vk1, Gi[r][c1]);
            }
            __syncthreads();
        }
    }

    // E = Z @ G^{-1}  (G^{-1} lives in Gi[:][16..31])
    {
        float acc[8] = {};
        for (int r = 0; r < NQ; ++r) {
            float z = Zs[o][r];
            #pragma unroll
            for (int j = 0; j < 8; ++j) acc[j] = fmaf(z, Gi[r][NQ + qh + j], acc[j]);
        }
        #pragma unroll
        for (int j = 0; j < 8; ++j) Es[o][qh + j] = acc[j];
    }
    __syncthreads();

    // P2 = E @ Z^T  -> global (row-major 128x128 per batch)
    {
        float* P2b = P2 + (size_t)b * KFC;
        int ti = t >> 4, tj = t & 15;
        for (int ii = 0; ii < 8; ++ii) {
            int i = ti * 8 + ii;
            float acc[8] = {};
            for (int r = 0; r < NQ; ++r) {
                float e = Es[i][r];
                #pragma unroll
                for (int j = 0; j < 8; ++j)
                    acc[j] = fmaf(e, Zs[tj * 8 + j][r], acc[j]);
            }
            #pragma unroll
            for (int j = 0; j < 8; ++j)
                P2b[(size_t)i * D2 + tj * 8 + j] = acc[j];
        }
    }
}

// ---------------------------------------------------------------------------
// K3: split-K GEMM  part[ks][c][b] = sum_{k in chunk} P2[b][k] * fcw[c][k]
// grid = (4 batch-tiles of 64, 64 K-splits of 256), 256 threads
// ---------------------------------------------------------------------------
__global__ __launch_bounds__(256) void k_fc(const float* __restrict__ P2,
                                            const float* __restrict__ fcw,
                                            float* __restrict__ part) {
    __shared__ float As[FC_BM][FC_BK + 1];   // [b][k]
    __shared__ float Bs[112][FC_BK + 1];     // [c][k], c padded to 112 (zeros)

    int bt = blockIdx.x;                 // 0..3
    int ks = blockIdx.y;                 // 0..63
    int t  = threadIdx.x;
    int b0 = bt * FC_BM;
    int k0 = ks * FC_KCHUNK;
    int tb = t >> 4;                     // 16 groups -> 4 b each
    int tc = t & 15;                     // 16 groups -> 7 c each (112 padded)

    float acc[4][7] = {};

    for (int kt = 0; kt < FC_KCHUNK / FC_BK; ++kt) {   // 8 tiles
        int kk0 = k0 + kt * FC_BK;
        for (int l = t; l < FC_BM * FC_BK; l += 256) {
            int bi = l >> 5, kk = l & 31;
            As[bi][kk] = P2[(size_t)(b0 + bi) * KFC + kk0 + kk];
        }
        for (int l = t; l < 112 * FC_BK; l += 256) {
            int c = l >> 5, kk = l & 31;
            Bs[c][kk] = (c < NC) ? fcw[(size_t)c * KFC + kk0 + kk] : 0.f;
        }
        __syncthreads();
        for (int k = 0; k < FC_BK; ++k) {
            float a[4], bb[7];
            #pragma unroll
            for (int j = 0; j < 4; ++j) a[j] = As[tb * 4 + j][k];
            #pragma unroll
            for (int j = 0; j < 7; ++j) bb[j] = Bs[tc * 7 + j][k];
            #pragma unroll
            for (int i = 0; i < 4; ++i)
                #pragma unroll
                for (int j = 0; j < 7; ++j)
                    acc[i][j] = fmaf(a[i], bb[j], acc[i][j]);
        }
        __syncthreads();
    }

    #pragma unroll
    for (int j = 0; j < 7; ++j) {
        int c = tc * 7 + j;
        if (c < NC) {
            #pragma unroll
            for (int i = 0; i < 4; ++i)
                part[((size_t)ks * NC + c) * BATCH + b0 + tb * 4 + i] = acc[i][j];
        }
    }
}

// ---------------------------------------------------------------------------
// K4: out[b][c] = fcb[c] + sum_ks part[ks][c][b]   (deterministic reduce)
// ---------------------------------------------------------------------------
__global__ __launch_bounds__(256) void k_reduce(const float* __restrict__ part,
                                                const float* __restrict__ fcb,
                                                float* __restrict__ out) {
    int c = blockIdx.x;        // 0..99
    int bb = threadIdx.x;      // 0..255
    float s = fcb[c];
    for (int ks = 0; ks < FC_KS; ++ks)
        s += part[((size_t)ks * NC + c) * BATCH + bb];
    out[(size_t)bb * NC + c] = s;
}

extern "C" void kernel_launch(void* const* d_in, const int* in_sizes, int n_in,
                              void* d_out, int out_size, void* d_ws, size_t ws_size,
                              hipStream_t stream) {
    const float* X   = (const float*)d_in[0];   // (256, 512, 16)
    const float* W   = (const float*)d_in[1];   // (256, 512)
    const float* fcw = (const float*)d_in[2];   // (100, 16384)
    const float* fcb = (const float*)d_in[3];   // (100,)
    float* out = (float*)d_out;                 // (256, 100)

    float* ws   = (float*)d_ws;
    float* W2T  = ws;                              // 512*128      = 65536 floats
    float* P2   = W2T + (size_t)DIN * D2;          // 256*16384    = 4194304 floats
    float* part = P2 + (size_t)BATCH * KFC;        // 64*100*256   = 1638400 floats
    // total ws: ~23.6 MB

    k_poolw <<<dim3((DIN * D2) / 256), 256, 0, stream>>>(W, W2T);
    k_batch <<<dim3(BATCH),            256, 0, stream>>>(X, W2T, P2);
    k_fc    <<<dim3(FC_NBT, FC_KS),    256, 0, stream>>>(P2, fcw, part);
    k_reduce<<<dim3(NC),               256, 0, stream>>>(part, fcb, out);
}

// Round 2
// 78.284 us; speedup vs baseline: 1.6434x; 1.6434x over previous
//
#include <hip/hip_runtime.h>
#include <hip/hip_bf16.h>
#include <cstdint>

#define BATCH 256
#define DIN   512
#define D2    128
#define NQ    16
#define NC    100
#define KFC   (D2 * D2)      // 16384

#define KS    32             // K-splits for FC
#define KCH   (KFC / KS)     // 512
#define STEPS (KCH / 32)     // 16 MFMA K-steps per block

typedef short short8 __attribute__((ext_vector_type(8)));
typedef float f32x4  __attribute__((ext_vector_type(4)));

// ---------------------------------------------------------------------------
// K1: W2T[i][o] = 0.5*(W[2o][i] + W[2o+1][i])  -- pooled weight, transposed
// ---------------------------------------------------------------------------
__global__ __launch_bounds__(256) void k_poolw(const float* __restrict__ W,
                                               float* __restrict__ W2T) {
    int idx = blockIdx.x * 256 + threadIdx.x;   // 0 .. 65535
    int o = idx & (D2 - 1);
    int i = idx >> 7;
    W2T[(size_t)i * D2 + o] =
        0.5f * (W[(size_t)(2 * o) * DIN + i] + W[(size_t)(2 * o + 1) * DIN + i]);
}

// ---------------------------------------------------------------------------
// K1b: fcw (fp32) -> bf16, contiguous. n = NC*KFC = 1638400 = 800*256*8 exact.
// ---------------------------------------------------------------------------
__global__ __launch_bounds__(256) void k_cvt(const float* __restrict__ src,
                                             __hip_bfloat16* __restrict__ dst) {
    int i = (blockIdx.x * 256 + threadIdx.x) * 8;
    float4 a = *(const float4*)(src + i);
    float4 b = *(const float4*)(src + i + 4);
    short8 v;
    __hip_bfloat16* h = (__hip_bfloat16*)&v;
    h[0] = __float2bfloat16(a.x); h[1] = __float2bfloat16(a.y);
    h[2] = __float2bfloat16(a.z); h[3] = __float2bfloat16(a.w);
    h[4] = __float2bfloat16(b.x); h[5] = __float2bfloat16(b.y);
    h[6] = __float2bfloat16(b.z); h[7] = __float2bfloat16(b.w);
    *(short8*)(dst + i) = v;
}

// ---------------------------------------------------------------------------
// K2: per-batch block. Z = W2 @ X_b (128x16); G = Z^T Z; G^{-1} via
// Gauss-Jordan (SPD); E = Z G^{-1}; P2 = E Z^T  (projector), emitted as bf16.
// ---------------------------------------------------------------------------
__global__ __launch_bounds__(256) void k_batch(const float* __restrict__ X,
                                               const float* __restrict__ W2T,
                                               __hip_bfloat16* __restrict__ P2) {
    __shared__ float Xs[DIN][NQ];          // 32 KB
    __shared__ float Zs[D2][NQ + 1];       // padded
    __shared__ float Es[D2][NQ + 1];
    __shared__ float Gi[NQ][2 * NQ];       // [G | I] -> [I | G^{-1}]

    int b = blockIdx.x;
    int t = threadIdx.x;
    const float* Xb = X + (size_t)b * DIN * NQ;

    // stage X_b (coalesced, float4)
    {
        const float4* Xb4 = (const float4*)Xb;
        float4* Xs4 = (float4*)&Xs[0][0];
        for (int l = t; l < (DIN * NQ) / 4; l += 256)
            Xs4[l] = Xb4[l];
    }
    __syncthreads();

    int o  = t & (D2 - 1);
    int qh = (t >> 7) * 8;   // 0 or 8

    // Z = W2 @ X_b : each thread owns (o, 8 q's)
    {
        float acc[8] = {};
        #pragma unroll 4
        for (int i = 0; i < DIN; ++i) {
            float w = W2T[(size_t)i * D2 + o];   // coalesced, L2-resident
            #pragma unroll
            for (int j = 0; j < 8; ++j) acc[j] = fmaf(w, Xs[i][qh + j], acc[j]);
        }
        #pragma unroll
        for (int j = 0; j < 8; ++j) Zs[o][qh + j] = acc[j];
    }
    __syncthreads();

    // G = Z^T Z : 256 threads <-> 256 entries
    {
        int qq = t >> 4, rr = t & 15;
        float s = 0.f;
        for (int i = 0; i < D2; ++i) s = fmaf(Zs[i][qq], Zs[i][rr], s);
        Gi[qq][rr] = s;
        Gi[qq][NQ + rr] = (qq == rr) ? 1.f : 0.f;
    }
    __syncthreads();

    // Gauss-Jordan on [G | I] (SPD -> no pivoting). Thread t -> row r, cols c0,c1.
    {
        int r  = t >> 4;
        int c0 = t & 15;
        int c1 = c0 + NQ;
        for (int k = 0; k < NQ; ++k) {
            float piv = Gi[k][k];
            float fac = Gi[r][k];
            float vk0 = Gi[k][c0];
            float vk1 = Gi[k][c1];
            __syncthreads();
            float inv = 1.f / piv;
            if (r == k) {
                Gi[k][c0] = vk0 * inv;
                Gi[k][c1] = vk1 * inv;
            } else {
                float f = fac * inv;
                Gi[r][c0] = fmaf(-f, vk0, Gi[r][c0]);
                Gi[r][c1] = fmaf(-f, vk1, Gi[r][c1]);
            }
            __syncthreads();
        }
    }

    // E = Z @ G^{-1}  (G^{-1} lives in Gi[:][16..31])
    {
        float acc[8] = {};
        #pragma unroll
        for (int r = 0; r < NQ; ++r) {
            float z = Zs[o][r];
            #pragma unroll
            for (int j = 0; j < 8; ++j) acc[j] = fmaf(z, Gi[r][NQ + qh + j], acc[j]);
        }
        #pragma unroll
        for (int j = 0; j < 8; ++j) Es[o][qh + j] = acc[j];
    }
    __syncthreads();

    // P2 = E @ Z^T  -> global bf16 (row-major 128x128 per batch)
    {
        __hip_bfloat16* P2b = P2 + (size_t)b * KFC;
        int ti = t >> 4, tj = t & 15;
        for (int ii = 0; ii < 8; ++ii) {
            int i = ti * 8 + ii;
            float acc[8] = {};
            #pragma unroll
            for (int r = 0; r < NQ; ++r) {
                float e = Es[i][r];
                #pragma unroll
                for (int j = 0; j < 8; ++j)
                    acc[j] = fmaf(e, Zs[tj * 8 + j][r], acc[j]);
            }
            short8 v;
            __hip_bfloat16* h = (__hip_bfloat16*)&v;
            #pragma unroll
            for (int j = 0; j < 8; ++j) h[j] = __float2bfloat16(acc[j]);
            *(short8*)(P2b + (size_t)i * D2 + tj * 8) = v;
        }
    }
}

// ---------------------------------------------------------------------------
// K3: MFMA split-K FC.  part[ks][b][c] = sum_{k in chunk} P2[b][k]*fcw[c][k]
// grid = (16 bt, 32 ks), 256 threads = 4 waves; wave w covers classes
// [w*32, w*32+32) (padded to 128). Fragments loaded straight from global:
// A-frags (P2 rows) are identical across the 4 waves -> L1 hits; B-frags
// (fcw k-chunk) are shared across the 16 consecutive bt blocks -> L2 hits.
// ---------------------------------------------------------------------------
__global__ __launch_bounds__(256) void k_fc(const __hip_bfloat16* __restrict__ P2,
                                            const __hip_bfloat16* __restrict__ fcw16,
                                            float* __restrict__ part) {
    int bt = blockIdx.x;            // 0..15 (16 batches each)
    int ks = blockIdx.y;            // 0..31 (K chunk of 512)
    int t  = threadIdx.x;
    int lane = t & 63;
    int w    = t >> 6;              // wave id: class group
    int m  = lane & 15;             // A row / B col within tile
    int kg = (lane >> 4) * 8;       // k sub-offset within 32-wide step

    const __hip_bfloat16* pa =
        P2 + (size_t)(bt * 16 + m) * KFC + ks * KCH + kg;

    int c0 = w * 32 + m;            // class for n-tile 0
    int c1 = c0 + 16;               // class for n-tile 1
    bool v0 = (c0 < NC), v1 = (c1 < NC);
    const __hip_bfloat16* pb0 =
        fcw16 + (size_t)(v0 ? c0 : 0) * KFC + ks * KCH + kg;
    const __hip_bfloat16* pb1 =
        fcw16 + (size_t)(v1 ? c1 : 0) * KFC + ks * KCH + kg;

    f32x4 acc0 = {0.f, 0.f, 0.f, 0.f};
    f32x4 acc1 = {0.f, 0.f, 0.f, 0.f};
    short8 zz = {};

    #pragma unroll 4
    for (int s = 0; s < STEPS; ++s) {
        short8 a  = *(const short8*)(pa + s * 32);
        short8 b0 = v0 ? *(const short8*)(pb0 + s * 32) : zz;
        short8 b1 = v1 ? *(const short8*)(pb1 + s * 32) : zz;
        acc0 = __builtin_amdgcn_mfma_f32_16x16x32_bf16(a, b0, acc0, 0, 0, 0);
        acc1 = __builtin_amdgcn_mfma_f32_16x16x32_bf16(a, b1, acc1, 0, 0, 0);
    }

    // C layout: col = lane&15, row = (lane>>4)*4 + j
    int r0 = (lane >> 4) * 4;
    float* pp = part + ((size_t)ks * BATCH + bt * 16 + r0) * D2;
    #pragma unroll
    for (int j = 0; j < 4; ++j) {
        pp[(size_t)j * D2 + w * 32 + m]      = acc0[j];
        pp[(size_t)j * D2 + w * 32 + 16 + m] = acc1[j];
    }
}

// ---------------------------------------------------------------------------
// K4: out[b][c] = fcb[c] + sum_ks part[ks][b][c]   (deterministic, coalesced)
// ---------------------------------------------------------------------------
__global__ __launch_bounds__(128) void k_red(const float* __restrict__ part,
                                             const float* __restrict__ fcb,
                                             float* __restrict__ out) {
    int b = blockIdx.x;        // 0..255
    int c = threadIdx.x;       // 0..127
    if (c < NC) {
        float s = fcb[c];
        #pragma unroll 8
        for (int ks = 0; ks < KS; ++ks)
            s += part[((size_t)ks * BATCH + b) * D2 + c];
        out[(size_t)b * NC + c] = s;
    }
}

extern "C" void kernel_launch(void* const* d_in, const int* in_sizes, int n_in,
                              void* d_out, int out_size, void* d_ws, size_t ws_size,
                              hipStream_t stream) {
    const float* X   = (const float*)d_in[0];   // (256, 512, 16)
    const float* W   = (const float*)d_in[1];   // (256, 512)
    const float* fcw = (const float*)d_in[2];   // (100, 16384)
    const float* fcb = (const float*)d_in[3];   // (100,)
    float* out = (float*)d_out;                 // (256, 100)

    float* ws = (float*)d_ws;
    float*          W2T   = ws;                                   // 65536 f
    __hip_bfloat16* P2b16 = (__hip_bfloat16*)(ws + 65536);        // 4.19M bf16 (2097152 f)
    __hip_bfloat16* fcw16 = (__hip_bfloat16*)(ws + 65536 + 2097152);       // 1.64M bf16 (819200 f)
    float*          part  = ws + 65536 + 2097152 + 819200;        // 1048576 f (4 MB)
    // total ws ~= 16.1 MB

    k_poolw<<<dim3((DIN * D2) / 256), 256, 0, stream>>>(W, W2T);
    k_cvt  <<<dim3((NC * KFC) / (256 * 8)), 256, 0, stream>>>(fcw, fcw16);
    k_batch<<<dim3(BATCH), 256, 0, stream>>>(X, W2T, P2b16);
    k_fc   <<<dim3(16, KS), 256, 0, stream>>>(P2b16, fcw16, part);
    k_red  <<<dim3(BATCH), 128, 0, stream>>>(part, fcb, out);
}

// Round 3
// 54.756 us; speedup vs baseline: 2.3496x; 1.4297x over previous
//
#include <hip/hip_runtime.h>
#include <hip/hip_bf16.h>
#include <cstdint>

#define BATCH 256
#define DIN   512
#define D2    128
#define NQ    16
#define NC    100
#define KFC   (D2 * D2)      // 16384

#define ZKS   4              // K-splits for Z GEMM (512/4 = 128 per split)
#define ZKL   (DIN / ZKS)    // 128

#define KS    32             // K-splits for FC
#define KCH   (KFC / KS)     // 512
#define STEPS (KCH / 32)     // 16 MFMA K-steps per block

#define ZPAD  132            // Zt/Et row stride (floats): 16B-aligned, low-conflict

typedef short short8 __attribute__((ext_vector_type(8)));
typedef float f32x4  __attribute__((ext_vector_type(4)));

// ---------------------------------------------------------------------------
// K1: W2T[i][o] = 0.5*(W[2o][i] + W[2o+1][i])  -- pooled weight, transposed
// ---------------------------------------------------------------------------
__global__ __launch_bounds__(256) void k_poolw(const float* __restrict__ W,
                                               float* __restrict__ W2T) {
    int idx = blockIdx.x * 256 + threadIdx.x;   // 0 .. 65535
    int o = idx & (D2 - 1);
    int i = idx >> 7;
    W2T[(size_t)i * D2 + o] =
        0.5f * (W[(size_t)(2 * o) * DIN + i] + W[(size_t)(2 * o + 1) * DIN + i]);
}

// ---------------------------------------------------------------------------
// K1b: fcw (fp32) -> bf16, contiguous.
// ---------------------------------------------------------------------------
__global__ __launch_bounds__(256) void k_cvt(const float* __restrict__ src,
                                             __hip_bfloat16* __restrict__ dst) {
    int i = (blockIdx.x * 256 + threadIdx.x) * 8;
    float4 a = *(const float4*)(src + i);
    float4 b = *(const float4*)(src + i + 4);
    short8 v;
    __hip_bfloat16* h = (__hip_bfloat16*)&v;
    h[0] = __float2bfloat16(a.x); h[1] = __float2bfloat16(a.y);
    h[2] = __float2bfloat16(a.z); h[3] = __float2bfloat16(a.w);
    h[4] = __float2bfloat16(b.x); h[5] = __float2bfloat16(b.y);
    h[6] = __float2bfloat16(b.z); h[7] = __float2bfloat16(b.w);
    *(short8*)(dst + i) = v;
}

// ---------------------------------------------------------------------------
// K2a: split-K GEMM for Z.  Zp[ks][b][q][o] = sum_{i in split} W2[o][i]*X[b][i][q]
// grid (BATCH, ZKS), 256 threads. 1024 blocks -> ~4 blocks/CU.
// ---------------------------------------------------------------------------
__global__ __launch_bounds__(256) void k_z(const float* __restrict__ X,
                                           const float* __restrict__ W2T,
                                           float* __restrict__ Zp) {
    __shared__ float Xs[ZKL][NQ];   // 8 KB slice of X_b
    int b  = blockIdx.x;
    int ks = blockIdx.y;
    int t  = threadIdx.x;

    // stage X[b][ks*128 .. +128)[0..16)  (contiguous 2048 floats)
    {
        const float4* src = (const float4*)(X + ((size_t)b * DIN + ks * ZKL) * NQ);
        float4* dst = (float4*)&Xs[0][0];
        for (int l = t; l < (ZKL * NQ) / 4; l += 256) dst[l] = src[l];
    }
    __syncthreads();

    int o  = t & (D2 - 1);
    int qh = (t >> 7) * 8;   // 0 or 8

    float acc[8] = {};
    #pragma unroll 4
    for (int i = 0; i < ZKL; ++i) {
        float w = W2T[(size_t)(ks * ZKL + i) * D2 + o];   // coalesced, L2-hot
        #pragma unroll
        for (int j = 0; j < 8; ++j) acc[j] = fmaf(w, Xs[i][qh + j], acc[j]);
    }

    float* zp = Zp + ((size_t)(ks * BATCH + b) * NQ) * D2;
    #pragma unroll
    for (int j = 0; j < 8; ++j)
        zp[(size_t)(qh + j) * D2 + o] = acc[j];          // coalesced per q
}

// ---------------------------------------------------------------------------
// K2b: per-batch epilogue. Z = sum Zp; G = Z^T Z; GJ-invert; E = Z G^{-1};
// P2 = E Z^T -> bf16. All LDS layouts q-major (pad ZPAD) for conflict-free
// b128/b32 access.
// ---------------------------------------------------------------------------
__global__ __launch_bounds__(256) void k_gep(const float* __restrict__ Zp,
                                             __hip_bfloat16* __restrict__ P2) {
    __shared__ float Zt[NQ][ZPAD];    // Zt[q][o]
    __shared__ float Et[NQ][ZPAD];    // Et[q][o]
    __shared__ float Gi[NQ][34];      // [G | I] -> [I | G^{-1}]

    int b = blockIdx.x;
    int t = threadIdx.x;

    // phase 1: reduce the ZKS partials, write q-major
    for (int l = t; l < NQ * D2; l += 256) {
        float s = 0.f;
        #pragma unroll
        for (int ks = 0; ks < ZKS; ++ks)
            s += Zp[((size_t)(ks * BATCH + b) * NQ) * D2 + l];
        Zt[l >> 7][l & (D2 - 1)] = s;
    }
    __syncthreads();

    // phase 2: G = Z^T Z  (256 threads <-> 256 entries)
    {
        int qq = t >> 4, rr = t & 15;
        float s = 0.f;
        for (int i = 0; i < D2; i += 4) {
            float4 a = *(const float4*)&Zt[qq][i];
            float4 c = *(const float4*)&Zt[rr][i];
            s = fmaf(a.x, c.x, s); s = fmaf(a.y, c.y, s);
            s = fmaf(a.z, c.z, s); s = fmaf(a.w, c.w, s);
        }
        Gi[qq][rr] = s;
        Gi[qq][NQ + rr] = (qq == rr) ? 1.f : 0.f;
    }
    __syncthreads();

    // phase 3: Gauss-Jordan on [G | I]  (SPD -> no pivoting)
    {
        int r  = t >> 4;
        int c0 = t & 15;
        int c1 = c0 + NQ;
        for (int k = 0; k < NQ; ++k) {
            float piv = Gi[k][k];
            float fac = Gi[r][k];
            float vk0 = Gi[k][c0];
            float vk1 = Gi[k][c1];
            __syncthreads();
            float inv = 1.f / piv;
            if (r == k) {
                Gi[k][c0] = vk0 * inv;
                Gi[k][c1] = vk1 * inv;
            } else {
                float f = fac * inv;
                Gi[r][c0] = fmaf(-f, vk0, Gi[r][c0]);
                Gi[r][c1] = fmaf(-f, vk1, Gi[r][c1]);
            }
            __syncthreads();
        }
    }

    // phase 4: E = Z G^{-1}, stored q-major. Thread (o, qh).
    {
        int o  = t & (D2 - 1);
        int qh = (t >> 7) * 8;
        float acc[8] = {};
        #pragma unroll
        for (int rp = 0; rp < NQ; ++rp) {
            float z = Zt[rp][o];                      // contiguous b32
            #pragma unroll
            for (int j = 0; j < 8; ++j)
                acc[j] = fmaf(z, Gi[rp][NQ + qh + j], acc[j]);   // broadcast
        }
        #pragma unroll
        for (int j = 0; j < 8; ++j) Et[qh + j][o] = acc[j];
    }
    __syncthreads();

    // phase 5: P2 = E Z^T -> global bf16. Thread (ti, tj): rows ti*8+ii, cols tj*8..+7
    {
        __hip_bfloat16* P2b = P2 + (size_t)b * KFC;
        int ti = t >> 4, tj = t & 15;
        for (int ii = 0; ii < 8; ++ii) {
            int i = ti * 8 + ii;
            float acc[8] = {};
            #pragma unroll
            for (int r = 0; r < NQ; ++r) {
                float e  = Et[r][i];                        // 4-addr broadcast
                float4 z0 = *(const float4*)&Zt[r][tj * 8];     // aligned b128
                float4 z1 = *(const float4*)&Zt[r][tj * 8 + 4];
                acc[0] = fmaf(e, z0.x, acc[0]); acc[1] = fmaf(e, z0.y, acc[1]);
                acc[2] = fmaf(e, z0.z, acc[2]); acc[3] = fmaf(e, z0.w, acc[3]);
                acc[4] = fmaf(e, z1.x, acc[4]); acc[5] = fmaf(e, z1.y, acc[5]);
                acc[6] = fmaf(e, z1.z, acc[6]); acc[7] = fmaf(e, z1.w, acc[7]);
            }
            short8 v;
            __hip_bfloat16* h = (__hip_bfloat16*)&v;
            #pragma unroll
            for (int j = 0; j < 8; ++j) h[j] = __float2bfloat16(acc[j]);
            *(short8*)(P2b + (size_t)i * D2 + tj * 8) = v;
        }
    }
}

// ---------------------------------------------------------------------------
// K3: MFMA split-K FC.  part[ks][b][c] = sum_{k in chunk} P2[b][k]*fcw[c][k]
// ---------------------------------------------------------------------------
__global__ __launch_bounds__(256) void k_fc(const __hip_bfloat16* __restrict__ P2,
                                            const __hip_bfloat16* __restrict__ fcw16,
                                            float* __restrict__ part) {
    int bt = blockIdx.x;            // 0..15
    int ks = blockIdx.y;            // 0..31
    int t  = threadIdx.x;
    int lane = t & 63;
    int w    = t >> 6;
    int m  = lane & 15;
    int kg = (lane >> 4) * 8;

    const __hip_bfloat16* pa =
        P2 + (size_t)(bt * 16 + m) * KFC + ks * KCH + kg;

    int c0 = w * 32 + m;
    int c1 = c0 + 16;
    bool v0 = (c0 < NC), v1 = (c1 < NC);
    const __hip_bfloat16* pb0 =
        fcw16 + (size_t)(v0 ? c0 : 0) * KFC + ks * KCH + kg;
    const __hip_bfloat16* pb1 =
        fcw16 + (size_t)(v1 ? c1 : 0) * KFC + ks * KCH + kg;

    f32x4 acc0 = {0.f, 0.f, 0.f, 0.f};
    f32x4 acc1 = {0.f, 0.f, 0.f, 0.f};
    short8 zz = {};

    #pragma unroll 4
    for (int s = 0; s < STEPS; ++s) {
        short8 a  = *(const short8*)(pa + s * 32);
        short8 b0 = v0 ? *(const short8*)(pb0 + s * 32) : zz;
        short8 b1 = v1 ? *(const short8*)(pb1 + s * 32) : zz;
        acc0 = __builtin_amdgcn_mfma_f32_16x16x32_bf16(a, b0, acc0, 0, 0, 0);
        acc1 = __builtin_amdgcn_mfma_f32_16x16x32_bf16(a, b1, acc1, 0, 0, 0);
    }

    int r0 = (lane >> 4) * 4;
    float* pp = part + ((size_t)ks * BATCH + bt * 16 + r0) * D2;
    #pragma unroll
    for (int j = 0; j < 4; ++j) {
        pp[(size_t)j * D2 + w * 32 + m]      = acc0[j];
        pp[(size_t)j * D2 + w * 32 + 16 + m] = acc1[j];
    }
}

// ---------------------------------------------------------------------------
// K4: out[b][c] = fcb[c] + sum_ks part[ks][b][c]
// ---------------------------------------------------------------------------
__global__ __launch_bounds__(128) void k_red(const float* __restrict__ part,
                                             const float* __restrict__ fcb,
                                             float* __restrict__ out) {
    int b = blockIdx.x;
    int c = threadIdx.x;
    if (c < NC) {
        float s = fcb[c];
        #pragma unroll 8
        for (int ks = 0; ks < KS; ++ks)
            s += part[((size_t)ks * BATCH + b) * D2 + c];
        out[(size_t)b * NC + c] = s;
    }
}

extern "C" void kernel_launch(void* const* d_in, const int* in_sizes, int n_in,
                              void* d_out, int out_size, void* d_ws, size_t ws_size,
                              hipStream_t stream) {
    const float* X   = (const float*)d_in[0];   // (256, 512, 16)
    const float* W   = (const float*)d_in[1];   // (256, 512)
    const float* fcw = (const float*)d_in[2];   // (100, 16384)
    const float* fcb = (const float*)d_in[3];   // (100,)
    float* out = (float*)d_out;                 // (256, 100)

    float* ws = (float*)d_ws;
    float*          W2T   = ws;                                  // 65536 f
    float*          Zp    = ws + 65536;                          // 4*256*2048 = 2097152 f (8 MB)
    float*          part  = Zp;                                  // aliased: dead after k_gep
    __hip_bfloat16* P2b16 = (__hip_bfloat16*)(ws + 65536 + 2097152);            // 2097152 f
    __hip_bfloat16* fcw16 = (__hip_bfloat16*)(ws + 65536 + 2097152 + 2097152);  // 819200 f
    // total ws ~= 20.3 MB

    k_poolw<<<dim3((DIN * D2) / 256), 256, 0, stream>>>(W, W2T);
    k_cvt  <<<dim3((NC * KFC) / (256 * 8)), 256, 0, stream>>>(fcw, fcw16);
    k_z    <<<dim3(BATCH, ZKS), 256, 0, stream>>>(X, W2T, Zp);
    k_gep  <<<dim3(BATCH), 256, 0, stream>>>(Zp, P2b16);
    k_fc   <<<dim3(16, KS), 256, 0, stream>>>(P2b16, fcw16, part);
    k_red  <<<dim3(BATCH), 128, 0, stream>>>(part, fcb, out);
}